// Round 14
// baseline (525.913 us; speedup 1.0000x reference)
//
#include <hip/hip_runtime.h>
#include <hip/hip_bf16.h>
#include <math.h>

#define F_IN 200
#define HDIM 64
#define NPG  400
#define EPG  6400
#define KSEL 200   // NPG/2

typedef __attribute__((ext_vector_type(4))) float f32x4;
typedef __attribute__((ext_vector_type(8))) short s16x8;

__device__ __forceinline__ void gload_lds16(const void* g, void* l) {
    __builtin_amdgcn_global_load_lds(
        (const __attribute__((address_space(1))) void*)g,
        (__attribute__((address_space(3))) void*)l, 16, 0, 0);
}

// RNE float -> bf16 bits
__device__ __forceinline__ unsigned int bf16_rne(float x) {
    unsigned int b = __float_as_uint(x);
    return (b + 0x7FFFu + ((b >> 16) & 1u)) >> 16;
}

// split x into bf16 hi + bf16 lo (x ~= hi + lo, rel err ~2^-17)
__device__ __forceinline__ void split8(f32x4 v0, f32x4 v1, s16x8& h, s16x8& l) {
    float x[8] = {v0.x, v0.y, v0.z, v0.w, v1.x, v1.y, v1.z, v1.w};
#pragma unroll
    for (int j = 0; j < 8; j++) {
        unsigned int hb = bf16_rne(x[j]);
        float hf = __uint_as_float(hb << 16);
        float r = x[j] - hf;
        unsigned int lb = bf16_rne(r);
        h[j] = (short)hb;
        l[j] = (short)lb;
    }
}

// ---------------- pack W ([K,64]|[K,64] fp32) -> fragment-ordered bf16 pairs --
__global__ void pack_wf(const float* __restrict__ Wl, const float* __restrict__ Wr,
                        short* __restrict__ WF, int K, int KC) {
    int idx = blockIdx.x * blockDim.x + threadIdx.x;
    if (idx >= KC * 4096) return;
    int j    = idx & 7;
    int lane = (idx >> 3) & 63;
    int nf   = (idx >> 9) & 7;
    int kc   = idx >> 12;
    int k = kc * 32 + (lane >> 4) * 8 + j;
    int n = nf * 16 + (lane & 15);
    float v = 0.f;
    if (k < K) v = (n < 64) ? Wl[k * 64 + n] : Wr[k * 64 + (n - 64)];
    unsigned int hb = bf16_rne(v);
    float hf = __uint_as_float(hb << 16);
    unsigned int lb = bf16_rne(v - hf);
    WF[(size_t)((kc * 8 + nf) * 2 + 0) * 512 + lane * 8 + j] = (short)hb;
    WF[(size_t)((kc * 8 + nf) * 2 + 1) * 512 + lane * 8 + j] = (short)lb;
}

// ---------------- pack combine-W: [Wl;Wr] (K=128, 4 n-frags) ----------------
__global__ void pack_wf4(const float* __restrict__ Wl, const float* __restrict__ Wr,
                         short* __restrict__ WF) {
    int idx = blockIdx.x * blockDim.x + threadIdx.x;
    if (idx >= 4 * 2048) return;                 // 4 kc x 4 nf x 512
    int j    = idx & 7;
    int lane = (idx >> 3) & 63;
    int nf   = (idx >> 9) & 3;
    int kc   = idx >> 11;
    int k = kc * 32 + (lane >> 4) * 8 + j;
    int n = nf * 16 + (lane & 15);
    float v = (k < 64) ? Wl[k * 64 + n] : Wr[(k - 64) * 64 + n];
    unsigned int hb = bf16_rne(v);
    float hf = __uint_as_float(hb << 16);
    unsigned int lb = bf16_rne(v - hf);
    WF[(size_t)((kc * 4 + nf) * 2 + 0) * 512 + lane * 8 + j] = (short)hb;
    WF[(size_t)((kc * 4 + nf) * 2 + 1) * 512 + lane * 8 + j] = (short)lb;
}

// ---------------- layer-1 MFMA GEMM (R11-proven) ----------------------------
template <int K, int LDX, int KC, int TAIL>
__global__ __launch_bounds__(256) void gemm_lds(const float* __restrict__ X,
                                                const short* __restrict__ WF,
                                                float* __restrict__ O) {
    __shared__ float Xs[2][128 * 32];    // 2 x 16 KB
    __shared__ short Ws[2][8 * 2 * 512]; // 2 x 16 KB
    const int tid  = threadIdx.x;
    const int lane = tid & 63;
    const int wave = tid >> 6;
    const size_t rowbase = (size_t)blockIdx.x * 128;
    const f32x4 zero4 = (f32x4){0.f, 0.f, 0.f, 0.f};

    const int srow_off = wave * 32 + (lane >> 3);
    const int sbyte    = 16 * ((lane & 7) ^ (lane >> 3));

#define DMA_CHUNK(b, kc_) {                                                      \
    _Pragma("unroll")                                                            \
    for (int j = 0; j < 4; j++) {                                                \
        const char* xsrc = (const char*)X +                                      \
            (rowbase + srow_off + j * 8) * (size_t)(LDX * 4) + (kc_) * 128 + sbyte; \
        gload_lds16(xsrc, (char*)&Xs[b][0] + wave * 4096 + j * 1024);            \
        const short* wsrc = WF + (size_t)(kc_) * 8192 + wave * 2048 + j * 512 + lane * 8; \
        gload_lds16(wsrc, (char*)&Ws[b][0] + wave * 4096 + j * 1024);            \
    } }

    f32x4 acc[2][8];
#pragma unroll
    for (int m = 0; m < 2; m++)
#pragma unroll
        for (int nf = 0; nf < 8; nf++) acc[m][nf] = zero4;

    DMA_CHUNK(0, 0);
    __syncthreads();

    for (int kc = 0; kc < KC; kc++) {
        const int b = kc & 1;
        if (kc + 1 < KC) DMA_CHUNK(b ^ 1, kc + 1);

        s16x8 ah[2], al[2];
#pragma unroll
        for (int m = 0; m < 2; m++) {
            const int lr = wave * 32 + m * 16 + (lane & 15);
            const int g0 = (lane >> 4) * 2;
            f32x4 v0 = *(const f32x4*)&Xs[b][lr * 32 + 4 * (g0 ^ (lane & 7))];
            f32x4 v1 = *(const f32x4*)&Xs[b][lr * 32 + 4 * ((g0 + 1) ^ (lane & 7))];
            split8(v0, v1, ah[m], al[m]);
        }
#pragma unroll
        for (int nf = 0; nf < 8; nf++) {
            s16x8 wh = *(const s16x8*)&Ws[b][(nf * 2 + 0) * 512 + lane * 8];
            s16x8 wl = *(const s16x8*)&Ws[b][(nf * 2 + 1) * 512 + lane * 8];
#pragma unroll
            for (int m = 0; m < 2; m++) {
                acc[m][nf] = __builtin_amdgcn_mfma_f32_16x16x32_bf16(ah[m], wh, acc[m][nf], 0, 0, 0);
                acc[m][nf] = __builtin_amdgcn_mfma_f32_16x16x32_bf16(al[m], wh, acc[m][nf], 0, 0, 0);
                acc[m][nf] = __builtin_amdgcn_mfma_f32_16x16x32_bf16(ah[m], wl, acc[m][nf], 0, 0, 0);
            }
        }
        __syncthreads();
    }
#undef DMA_CHUNK

    if constexpr (TAIL > 0) {
        s16x8 ah[2], al[2];
#pragma unroll
        for (int m = 0; m < 2; m++) {
            const size_t row = rowbase + wave * 32 + m * 16 + (lane & 15);
            const int k0 = KC * 32 + (lane >> 4) * 8;
            f32x4 v0 = (k0 + 4 <= K) ? *(const f32x4*)&X[row * (size_t)LDX + k0] : zero4;
            f32x4 v1 = (k0 + 8 <= K) ? *(const f32x4*)&X[row * (size_t)LDX + k0 + 4] : zero4;
            split8(v0, v1, ah[m], al[m]);
        }
#pragma unroll
        for (int nf = 0; nf < 8; nf++) {
            s16x8 wh = *(const s16x8*)&WF[(size_t)((KC * 8 + nf) * 2 + 0) * 512 + lane * 8];
            s16x8 wl = *(const s16x8*)&WF[(size_t)((KC * 8 + nf) * 2 + 1) * 512 + lane * 8];
#pragma unroll
            for (int m = 0; m < 2; m++) {
                acc[m][nf] = __builtin_amdgcn_mfma_f32_16x16x32_bf16(ah[m], wh, acc[m][nf], 0, 0, 0);
                acc[m][nf] = __builtin_amdgcn_mfma_f32_16x16x32_bf16(al[m], wh, acc[m][nf], 0, 0, 0);
                acc[m][nf] = __builtin_amdgcn_mfma_f32_16x16x32_bf16(ah[m], wl, acc[m][nf], 0, 0, 0);
            }
        }
    }

    float* cs0 = &Xs[0][wave * 1024];
    float* cs1 = &Xs[1][wave * 1024];
#pragma unroll
    for (int m = 0; m < 2; m++) {
        const int scol = lane & 15;
        const int srow = (lane >> 4) * 4;
#pragma unroll
        for (int nf = 0; nf < 8; nf++)
#pragma unroll
            for (int r = 0; r < 4; r++) {
                int cr = srow + r;
                float* p = (cr < 8) ? cs0 + cr * 128 : cs1 + (cr - 8) * 128;
                p[nf * 16 + scol] = acc[m][nf][r];
            }
#pragma unroll
        for (int ps = 0; ps < 8; ps++) {
            int row = ps * 2 + (lane >> 5);
            const float* p = (row < 8) ? cs0 + row * 128 : cs1 + (row - 8) * 128;
            f32x4 v = *(const f32x4*)&p[(lane & 31) * 4];
            *(f32x4*)&O[(rowbase + wave * 32 + m * 16 + row) * 128 + (lane & 31) * 4] = v;
        }
    }
}

// ---------------- combine GEMM (R12-proven): P = relu([M|H]@Wc+b)+resid -----
__global__ __launch_bounds__(1024) void combine_gemm(
    const float* __restrict__ M, const float* __restrict__ H,
    const short* __restrict__ WF, const float* __restrict__ bias,
    const float* __restrict__ resid, float* __restrict__ P)
{
    __shared__ float Xs[2][256 * 32];    // 2 x 32 KB
    __shared__ short Ws[2][4 * 2 * 512]; // 2 x 8 KB
    const int tid  = threadIdx.x;
    const int lane = tid & 63;
    const int wave = tid >> 6;
    const size_t rowbase = (size_t)blockIdx.x * 256;

#define DMA_C(b, c_) {                                                           \
    const float* srcbuf_ = ((c_) < 2) ? M : H;                                   \
    _Pragma("unroll")                                                            \
    for (int i = 0; i < 2; i++) {                                                \
        int rr = i * 8 + (lane >> 3);                                            \
        int jj = (lane & 7) ^ (rr & 7);                                          \
        const char* src = (const char*)(srcbuf_ + (rowbase + wave * 16 + rr) * 64) \
                          + ((c_) & 1) * 128 + jj * 16;                          \
        gload_lds16(src, (char*)&Xs[b][0] + wave * 2048 + i * 1024 + lane * 16); \
    }                                                                            \
    if (tid < 512) {                                                             \
        const short* wsrc = WF + (size_t)(c_) * 4096 + tid * 8;                  \
        gload_lds16(wsrc, (char*)&Ws[b][0] + tid * 16);                          \
    } }

    f32x4 acc[4];
#pragma unroll
    for (int nf = 0; nf < 4; nf++) acc[nf] = (f32x4){0.f, 0.f, 0.f, 0.f};

    DMA_C(0, 0);
    __syncthreads();

    for (int c = 0; c < 4; c++) {
        const int b = c & 1;
        if (c + 1 < 4) DMA_C(b ^ 1, c + 1);

        const int r = lane & 15;
        const int j0 = (lane >> 4) * 2;
        const float* abase = &Xs[b][wave * 512 + r * 32];
        f32x4 v0 = *(const f32x4*)&abase[((j0    ) ^ (r & 7)) * 4];
        f32x4 v1 = *(const f32x4*)&abase[((j0 + 1) ^ (r & 7)) * 4];
        s16x8 ah, al;
        split8(v0, v1, ah, al);
#pragma unroll
        for (int nf = 0; nf < 4; nf++) {
            s16x8 wh = *(const s16x8*)&Ws[b][(nf * 2 + 0) * 512 + lane * 8];
            s16x8 wl = *(const s16x8*)&Ws[b][(nf * 2 + 1) * 512 + lane * 8];
            acc[nf] = __builtin_amdgcn_mfma_f32_16x16x32_bf16(ah, wh, acc[nf], 0, 0, 0);
            acc[nf] = __builtin_amdgcn_mfma_f32_16x16x32_bf16(al, wh, acc[nf], 0, 0, 0);
            acc[nf] = __builtin_amdgcn_mfma_f32_16x16x32_bf16(ah, wl, acc[nf], 0, 0, 0);
        }
        __syncthreads();
    }
#undef DMA_C

    {
        const int scol = lane & 15;
        const int srow = (lane >> 4) * 4;
#pragma unroll
        for (int nf = 0; nf < 4; nf++)
#pragma unroll
            for (int ri = 0; ri < 4; ri++) {
                int cr = srow + ri;
                float* p = (cr < 8) ? &Xs[0][wave * 512 + cr * 64]
                                    : &Xs[1][wave * 512 + (cr - 8) * 64];
                p[nf * 16 + scol] = acc[nf][ri];
            }
#pragma unroll
        for (int i = 0; i < 4; i++) {
            int row = i * 4 + (lane >> 4);
            int col = (lane & 15) * 4;
            const float* p = (row < 8) ? &Xs[0][wave * 512 + row * 64]
                                       : &Xs[1][wave * 512 + (row - 8) * 64];
            f32x4 v = *(const f32x4*)&p[col];
            size_t grow = rowbase + wave * 16 + row;
            f32x4 bb = *(const f32x4*)&bias[col];
            f32x4 rr = *(const f32x4*)&resid[grow * 64 + col];
            f32x4 o;
#pragma unroll
            for (int q = 0; q < 4; q++) o[q] = fmaxf(v[q] + bb[q], 0.f) + rr[q];
            *(f32x4*)&P[grow * 64 + col] = o;
        }
    }
}

// ---------------- CSR build: one block per graph ----------------
__global__ __launch_bounds__(256) void csr_build(
    const int* __restrict__ esrc, const int* __restrict__ edst,
    int* __restrict__ csr_src, int* __restrict__ rowptr,
    int* __restrict__ degs, float* __restrict__ invdeg)
{
    __shared__ int cnt[NPG];
    __shared__ int off[NPG];
    __shared__ int cur[NPG];
    const int g = blockIdx.x, tid = threadIdx.x;
    const int ebase = g * EPG, nodebase = g * NPG;
    for (int i = tid; i < NPG; i += 256) cnt[i] = 0;
    __syncthreads();
    for (int e = tid; e < EPG; e += 256)
        atomicAdd(&cnt[edst[ebase + e] - nodebase], 1);
    __syncthreads();
    if (tid == 0) {
        int run = 0;
        for (int i = 0; i < NPG; i++) { off[i] = run; run += cnt[i]; }
    }
    __syncthreads();
    for (int i = tid; i < NPG; i += 256) {
        cur[i] = off[i];
        rowptr[nodebase + i] = off[i];
        degs[nodebase + i] = cnt[i];
        invdeg[nodebase + i] = 1.f / fmaxf((float)cnt[i], 1.f);
    }
    __syncthreads();
    for (int e = tid; e < EPG; e += 256) {
        int ld = edst[ebase + e] - nodebase;
        int p = atomicAdd(&cur[ld], 1);
        csr_src[ebase + p] = esrc[ebase + e] - nodebase;  // local src
    }
}

// ---------------- layer-1 aggregate+combine (reads A [N,128]) ----------------
__global__ __launch_bounds__(1024) void agg_lds(
    const float* __restrict__ A,
    const int* __restrict__ csr_src, const int* __restrict__ rowptr,
    const int* __restrict__ degs, const float* __restrict__ invdeg,
    const float* __restrict__ bias,
    float* __restrict__ Xout)
{
    __shared__ float y[NPG * 64];     // 102400 B
    __shared__ int   csr_l[EPG];      // 25600 B
    const int g = blockIdx.x, tid = threadIdx.x;
    const int ebase = g * EPG, nodebase = g * NPG;

    for (int idx = tid; idx < NPG * 16; idx += 1024) {
        int node = idx >> 4, c4 = (idx & 15) * 4;
        *(float4*)&y[node * 64 + c4] =
            *(const float4*)&A[(size_t)(nodebase + node) * 128 + c4];
    }
    for (int e = tid; e < EPG; e += 1024) csr_l[e] = csr_src[ebase + e];
    __syncthreads();

    const int wave = tid >> 6, lane = tid & 63;
    for (int node = wave; node < NPG; node += 16) {
        const int start = rowptr[nodebase + node];
        const int dg = degs[nodebase + node];
        float acc = 0.f;
        int j = 0;
        for (; j + 4 <= dg; j += 4) {
            int s0 = csr_l[start + j];
            int s1 = csr_l[start + j + 1];
            int s2 = csr_l[start + j + 2];
            int s3 = csr_l[start + j + 3];
            acc += y[s0 * 64 + lane] + y[s1 * 64 + lane]
                 + y[s2 * 64 + lane] + y[s3 * 64 + lane];
        }
        for (; j < dg; j++) acc += y[csr_l[start + j] * 64 + lane];

        float v = acc * invdeg[nodebase + node] + bias[lane]
                + A[(size_t)(nodebase + node) * 128 + 64 + lane];
        Xout[(size_t)(nodebase + node) * 64 + lane] = fmaxf(v, 0.f);
    }
}

// ---------------- input-side aggregation: M = mean-agg(H) --------------------
__global__ __launch_bounds__(1024) void agg_in(
    const float* __restrict__ H,
    const int* __restrict__ csr_src, const int* __restrict__ rowptr,
    const int* __restrict__ degs, const float* __restrict__ invdeg,
    float* __restrict__ M)
{
    __shared__ float y[NPG * 64];     // 102400 B
    __shared__ int   csr_l[EPG];      // 25600 B
    const int g = blockIdx.x, tid = threadIdx.x;
    const int ebase = g * EPG, nodebase = g * NPG;

    for (int idx = tid; idx < NPG * 16; idx += 1024) {
        int node = idx >> 4, c4 = (idx & 15) * 4;
        *(float4*)&y[node * 64 + c4] =
            *(const float4*)&H[(size_t)(nodebase + node) * 64 + c4];
    }
    for (int e = tid; e < EPG; e += 1024) csr_l[e] = csr_src[ebase + e];
    __syncthreads();

    const int wave = tid >> 6, lane = tid & 63;
    for (int node = wave; node < NPG; node += 16) {
        const int start = rowptr[nodebase + node];
        const int dg = degs[nodebase + node];
        float acc = 0.f;
        int j = 0;
        for (; j + 4 <= dg; j += 4) {
            int s0 = csr_l[start + j];
            int s1 = csr_l[start + j + 1];
            int s2 = csr_l[start + j + 2];
            int s3 = csr_l[start + j + 3];
            acc += y[s0 * 64 + lane] + y[s1 * 64 + lane]
                 + y[s2 * 64 + lane] + y[s3 * 64 + lane];
        }
        for (; j < dg; j++) acc += y[csr_l[start + j] * 64 + lane];

        M[(size_t)(nodebase + node) * 64 + lane] = acc * invdeg[nodebase + node];
    }
}

// ---------------- score+topk+pool+classifier, wave-parallel (R8-proven) ------
__global__ __launch_bounds__(1024) void score_pool2(
    const float* __restrict__ X3,
    const int* __restrict__ csr_src, const int* __restrict__ rowptr,
    const int* __restrict__ degs,
    const float* __restrict__ Wpr, const float* __restrict__ bpr,
    const float* __restrict__ Wpo,
    const float* __restrict__ Wlin, const float* __restrict__ blin,
    float* __restrict__ out)
{
    __shared__ int   csr_l[EPG];        // 25600 B
    __shared__ float t0s[NPG], ss[NPG], wsel[NPG];
    __shared__ float pp[16 * 64];
    __shared__ float pooled[64];
    __shared__ float lgs[2];
    const int g = blockIdx.x, tid = threadIdx.x;
    const int wave = tid >> 6, lane = tid & 63;
    const int nodebase = g * NPG, ebase = g * EPG;

    for (int e = tid; e < EPG; e += 1024) csr_l[e] = csr_src[ebase + e];

    // per-node scalars via wave-reduce (coalesced row reads)
    const float wpr = Wpr[lane], wpo = Wpo[lane];
    for (int node = wave; node < NPG; node += 16) {
        float v = X3[(size_t)(nodebase + node) * 64 + lane];
        float a = v * wpr, b = v * wpo;
#pragma unroll
        for (int o = 32; o; o >>= 1) { a += __shfl_xor(a, o); b += __shfl_xor(b, o); }
        if (lane == 0) { t0s[node] = a; ss[node] = bpr[0] + b; }
    }
    __syncthreads();
    // score edge aggregation (add) via CSR
    for (int node = wave; node < NPG; node += 16) {
        const int start = rowptr[nodebase + node];
        const int dg = degs[nodebase + node];
        float a = 0.f;
        for (int j = lane; j < dg; j += 64) a += t0s[csr_l[start + j]];
#pragma unroll
        for (int o = 32; o; o >>= 1) a += __shfl_xor(a, o);
        if (lane == 0) ss[node] += a;
    }
    __syncthreads();
    // stable top-k by counting (matches lax.top_k tie-breaking)
    if (tid < NPG) {
        float si = ss[tid];
        int cnt = 0;
        for (int j = 0; j < NPG; j++) {
            float sj = ss[j];
            cnt += (sj > si) || (sj == si && j < tid);
        }
        wsel[tid] = (cnt < KSEL) ? tanhf(si) * (1.f / KSEL) : 0.f;
    }
    __syncthreads();
    // tanh-weighted mean pool (coalesced)
    float a = 0.f;
    for (int node = wave; node < NPG; node += 16)
        a += wsel[node] * X3[(size_t)(nodebase + node) * 64 + lane];
    pp[wave * 64 + lane] = a;
    __syncthreads();
    if (tid < 64) {
        float s = 0.f;
#pragma unroll
        for (int i = 0; i < 16; i++) s += pp[i * 64 + tid];
        pooled[tid] = s;
    }
    __syncthreads();
    if (tid < 2) {
        float l = blin[tid];
        for (int d = 0; d < 64; d++) l += pooled[d] * Wlin[d * 2 + tid];
        lgs[tid] = l;
    }
    __syncthreads();
    if (tid < 2) {
        float m = fmaxf(lgs[0], lgs[1]);
        float lse = m + logf(expf(lgs[0] - m) + expf(lgs[1] - m));
        out[g * 2 + tid] = lgs[tid] - lse;
    }
}

extern "C" void kernel_launch(void* const* d_in, const int* in_sizes, int n_in,
                              void* d_out, int out_size, void* d_ws, size_t ws_size,
                              hipStream_t stream) {
    const float* x    = (const float*)d_in[0];
    const int*   eidx = (const int*)d_in[1];
    const float* W1l  = (const float*)d_in[3];
    const float* W1r  = (const float*)d_in[4];
    const float* b1   = (const float*)d_in[5];
    const float* W2l  = (const float*)d_in[6];
    const float* W2r  = (const float*)d_in[7];
    const float* b2   = (const float*)d_in[8];
    const float* W3l  = (const float*)d_in[9];
    const float* W3r  = (const float*)d_in[10];
    const float* b3   = (const float*)d_in[11];
    const float* Wpr  = (const float*)d_in[12];
    const float* bpr  = (const float*)d_in[13];
    const float* Wpo  = (const float*)d_in[14];
    const float* Wlin = (const float*)d_in[15];
    const float* blin = (const float*)d_in[16];

    const int N = in_sizes[0] / F_IN;       // 204800
    const int E = in_sizes[1] / 2;          // 3276800
    const int B = N / NPG;                  // 512
    const int* esrc = eidx;
    const int* edst = eidx + E;

    float* ws = (float*)d_ws;
    float* A      = ws;                                  // [N,128] layer-1 yz
    float* P0     = A + (size_t)N * 128;                 // [N,64]
    float* P1     = P0 + (size_t)N * 64;                 // [N,64]
    float* Mb     = P1 + (size_t)N * 64;                 // [N,64] mean-agg
    float* invdeg = Mb + (size_t)N * 64;                 // [N]
    short* WF1    = (short*)(invdeg + N);                // 7*8*2*512 shorts
    short* WFc2   = WF1 + 57344;                         // 4*4*2*512 shorts
    short* WFc3   = WFc2 + 16384;
    int*   csr    = (int*)(WFc3 + 16384);                // [E] local src by dst
    int*   rowptr = csr + E;                             // [N]
    int*   degs   = rowptr + N;                          // [N]

    pack_wf<<<(7 * 4096 + 255) / 256, 256, 0, stream>>>(W1l, W1r, WF1, 200, 7);
    pack_wf4<<<(4 * 2048 + 255) / 256, 256, 0, stream>>>(W2l, W2r, WFc2);
    pack_wf4<<<(4 * 2048 + 255) / 256, 256, 0, stream>>>(W3l, W3r, WFc3);

    // CSR once (shared by all layers + score)
    csr_build<<<B, 256, 0, stream>>>(esrc, edst, csr, rowptr, degs, invdeg);

    // layer 1: yz = x @ [W1l|W1r] -> A; x1 = relu(agg(y)+b+z) -> P0
    gemm_lds<200, 200, 6, 8><<<N / 128, 256, 0, stream>>>(x, WF1, A);
    agg_lds<<<B, 1024, 0, stream>>>(A, csr, rowptr, degs, invdeg, b1, P0);

    // layer 2 (m-form): M = mean-agg(P0); x2 = relu([M|P0]@Wc2 + b2) + P0 -> P1
    agg_in<<<B, 1024, 0, stream>>>(P0, csr, rowptr, degs, invdeg, Mb);
    combine_gemm<<<N / 256, 1024, 0, stream>>>(Mb, P0, WFc2, b2, P0, P1);

    // layer 3 (m-form): M = mean-agg(P1); x3 = relu([M|P1]@Wc3 + b3) + P1 -> P0
    agg_in<<<B, 1024, 0, stream>>>(P1, csr, rowptr, degs, invdeg, Mb);
    combine_gemm<<<N / 256, 1024, 0, stream>>>(Mb, P1, WFc3, b3, P1, P0);

    // score + top-k + pool + classifier (wave-parallel, CSR-based)
    score_pool2<<<B, 1024, 0, stream>>>(P0, csr, rowptr, degs,
                                        Wpr, bpr, Wpo, Wlin, blin,
                                        (float*)d_out);
}

// Round 15
// 465.767 us; speedup vs baseline: 1.1291x; 1.1291x over previous
//
#include <hip/hip_runtime.h>
#include <hip/hip_bf16.h>
#include <math.h>

#define F_IN 200
#define HDIM 64
#define NPG  400
#define EPG  6400
#define KSEL 200   // NPG/2

typedef __attribute__((ext_vector_type(4))) float f32x4;
typedef __attribute__((ext_vector_type(8))) short s16x8;

__device__ __forceinline__ void gload_lds16(const void* g, void* l) {
    __builtin_amdgcn_global_load_lds(
        (const __attribute__((address_space(1))) void*)g,
        (__attribute__((address_space(3))) void*)l, 16, 0, 0);
}

// RNE float -> bf16 bits
__device__ __forceinline__ unsigned int bf16_rne(float x) {
    unsigned int b = __float_as_uint(x);
    return (b + 0x7FFFu + ((b >> 16) & 1u)) >> 16;
}

// split x into bf16 hi + bf16 lo (x ~= hi + lo, rel err ~2^-17)
__device__ __forceinline__ void split8(f32x4 v0, f32x4 v1, s16x8& h, s16x8& l) {
    float x[8] = {v0.x, v0.y, v0.z, v0.w, v1.x, v1.y, v1.z, v1.w};
#pragma unroll
    for (int j = 0; j < 8; j++) {
        unsigned int hb = bf16_rne(x[j]);
        float hf = __uint_as_float(hb << 16);
        float r = x[j] - hf;
        unsigned int lb = bf16_rne(r);
        h[j] = (short)hb;
        l[j] = (short)lb;
    }
}

// ---------------- pack W ([K,64]|[K,64] fp32) -> fragment-ordered bf16 pairs --
__global__ void pack_wf(const float* __restrict__ Wl, const float* __restrict__ Wr,
                        short* __restrict__ WF, int K, int KC) {
    int idx = blockIdx.x * blockDim.x + threadIdx.x;
    if (idx >= KC * 4096) return;
    int j    = idx & 7;
    int lane = (idx >> 3) & 63;
    int nf   = (idx >> 9) & 7;
    int kc   = idx >> 12;
    int k = kc * 32 + (lane >> 4) * 8 + j;
    int n = nf * 16 + (lane & 15);
    float v = 0.f;
    if (k < K) v = (n < 64) ? Wl[k * 64 + n] : Wr[k * 64 + (n - 64)];
    unsigned int hb = bf16_rne(v);
    float hf = __uint_as_float(hb << 16);
    unsigned int lb = bf16_rne(v - hf);
    WF[(size_t)((kc * 8 + nf) * 2 + 0) * 512 + lane * 8 + j] = (short)hb;
    WF[(size_t)((kc * 8 + nf) * 2 + 1) * 512 + lane * 8 + j] = (short)lb;
}

// ---------------- pack combine-W: [Wl;Wr] (K=128, 4 n-frags) ----------------
__global__ void pack_wf4(const float* __restrict__ Wl, const float* __restrict__ Wr,
                         short* __restrict__ WF) {
    int idx = blockIdx.x * blockDim.x + threadIdx.x;
    if (idx >= 4 * 2048) return;                 // 4 kc x 4 nf x 512
    int j    = idx & 7;
    int lane = (idx >> 3) & 63;
    int nf   = (idx >> 9) & 3;
    int kc   = idx >> 11;
    int k = kc * 32 + (lane >> 4) * 8 + j;
    int n = nf * 16 + (lane & 15);
    float v = (k < 64) ? Wl[k * 64 + n] : Wr[(k - 64) * 64 + n];
    unsigned int hb = bf16_rne(v);
    float hf = __uint_as_float(hb << 16);
    unsigned int lb = bf16_rne(v - hf);
    WF[(size_t)((kc * 4 + nf) * 2 + 0) * 512 + lane * 8 + j] = (short)hb;
    WF[(size_t)((kc * 4 + nf) * 2 + 1) * 512 + lane * 8 + j] = (short)lb;
}

// ---------------- layer-1 MFMA GEMM (R11-proven) ----------------------------
template <int K, int LDX, int KC, int TAIL>
__global__ __launch_bounds__(256) void gemm_lds(const float* __restrict__ X,
                                                const short* __restrict__ WF,
                                                float* __restrict__ O) {
    __shared__ float Xs[2][128 * 32];    // 2 x 16 KB
    __shared__ short Ws[2][8 * 2 * 512]; // 2 x 16 KB
    const int tid  = threadIdx.x;
    const int lane = tid & 63;
    const int wave = tid >> 6;
    const size_t rowbase = (size_t)blockIdx.x * 128;
    const f32x4 zero4 = (f32x4){0.f, 0.f, 0.f, 0.f};

    const int srow_off = wave * 32 + (lane >> 3);
    const int sbyte    = 16 * ((lane & 7) ^ (lane >> 3));

#define DMA_CHUNK(b, kc_) {                                                      \
    _Pragma("unroll")                                                            \
    for (int j = 0; j < 4; j++) {                                                \
        const char* xsrc = (const char*)X +                                      \
            (rowbase + srow_off + j * 8) * (size_t)(LDX * 4) + (kc_) * 128 + sbyte; \
        gload_lds16(xsrc, (char*)&Xs[b][0] + wave * 4096 + j * 1024);            \
        const short* wsrc = WF + (size_t)(kc_) * 8192 + wave * 2048 + j * 512 + lane * 8; \
        gload_lds16(wsrc, (char*)&Ws[b][0] + wave * 4096 + j * 1024);            \
    } }

    f32x4 acc[2][8];
#pragma unroll
    for (int m = 0; m < 2; m++)
#pragma unroll
        for (int nf = 0; nf < 8; nf++) acc[m][nf] = zero4;

    DMA_CHUNK(0, 0);
    __syncthreads();

    for (int kc = 0; kc < KC; kc++) {
        const int b = kc & 1;
        if (kc + 1 < KC) DMA_CHUNK(b ^ 1, kc + 1);

        s16x8 ah[2], al[2];
#pragma unroll
        for (int m = 0; m < 2; m++) {
            const int lr = wave * 32 + m * 16 + (lane & 15);
            const int g0 = (lane >> 4) * 2;
            f32x4 v0 = *(const f32x4*)&Xs[b][lr * 32 + 4 * (g0 ^ (lane & 7))];
            f32x4 v1 = *(const f32x4*)&Xs[b][lr * 32 + 4 * ((g0 + 1) ^ (lane & 7))];
            split8(v0, v1, ah[m], al[m]);
        }
#pragma unroll
        for (int nf = 0; nf < 8; nf++) {
            s16x8 wh = *(const s16x8*)&Ws[b][(nf * 2 + 0) * 512 + lane * 8];
            s16x8 wl = *(const s16x8*)&Ws[b][(nf * 2 + 1) * 512 + lane * 8];
#pragma unroll
            for (int m = 0; m < 2; m++) {
                acc[m][nf] = __builtin_amdgcn_mfma_f32_16x16x32_bf16(ah[m], wh, acc[m][nf], 0, 0, 0);
                acc[m][nf] = __builtin_amdgcn_mfma_f32_16x16x32_bf16(al[m], wh, acc[m][nf], 0, 0, 0);
                acc[m][nf] = __builtin_amdgcn_mfma_f32_16x16x32_bf16(ah[m], wl, acc[m][nf], 0, 0, 0);
            }
        }
        __syncthreads();
    }
#undef DMA_CHUNK

    if constexpr (TAIL > 0) {
        s16x8 ah[2], al[2];
#pragma unroll
        for (int m = 0; m < 2; m++) {
            const size_t row = rowbase + wave * 32 + m * 16 + (lane & 15);
            const int k0 = KC * 32 + (lane >> 4) * 8;
            f32x4 v0 = (k0 + 4 <= K) ? *(const f32x4*)&X[row * (size_t)LDX + k0] : zero4;
            f32x4 v1 = (k0 + 8 <= K) ? *(const f32x4*)&X[row * (size_t)LDX + k0 + 4] : zero4;
            split8(v0, v1, ah[m], al[m]);
        }
#pragma unroll
        for (int nf = 0; nf < 8; nf++) {
            s16x8 wh = *(const s16x8*)&WF[(size_t)((KC * 8 + nf) * 2 + 0) * 512 + lane * 8];
            s16x8 wl = *(const s16x8*)&WF[(size_t)((KC * 8 + nf) * 2 + 1) * 512 + lane * 8];
#pragma unroll
            for (int m = 0; m < 2; m++) {
                acc[m][nf] = __builtin_amdgcn_mfma_f32_16x16x32_bf16(ah[m], wh, acc[m][nf], 0, 0, 0);
                acc[m][nf] = __builtin_amdgcn_mfma_f32_16x16x32_bf16(al[m], wh, acc[m][nf], 0, 0, 0);
                acc[m][nf] = __builtin_amdgcn_mfma_f32_16x16x32_bf16(ah[m], wl, acc[m][nf], 0, 0, 0);
            }
        }
    }

    float* cs0 = &Xs[0][wave * 1024];
    float* cs1 = &Xs[1][wave * 1024];
#pragma unroll
    for (int m = 0; m < 2; m++) {
        const int scol = lane & 15;
        const int srow = (lane >> 4) * 4;
#pragma unroll
        for (int nf = 0; nf < 8; nf++)
#pragma unroll
            for (int r = 0; r < 4; r++) {
                int cr = srow + r;
                float* p = (cr < 8) ? cs0 + cr * 128 : cs1 + (cr - 8) * 128;
                p[nf * 16 + scol] = acc[m][nf][r];
            }
#pragma unroll
        for (int ps = 0; ps < 8; ps++) {
            int row = ps * 2 + (lane >> 5);
            const float* p = (row < 8) ? cs0 + row * 128 : cs1 + (row - 8) * 128;
            f32x4 v = *(const f32x4*)&p[(lane & 31) * 4];
            *(f32x4*)&O[(rowbase + wave * 32 + m * 16 + row) * 128 + (lane & 31) * 4] = v;
        }
    }
}

// ---------------- combine GEMM (R12-proven): P = relu([M|H]@Wc+b)+resid -----
__global__ __launch_bounds__(1024) void combine_gemm(
    const float* __restrict__ M, const float* __restrict__ H,
    const short* __restrict__ WF, const float* __restrict__ bias,
    const float* __restrict__ resid, float* __restrict__ P)
{
    __shared__ float Xs[2][256 * 32];    // 2 x 32 KB
    __shared__ short Ws[2][4 * 2 * 512]; // 2 x 8 KB
    const int tid  = threadIdx.x;
    const int lane = tid & 63;
    const int wave = tid >> 6;
    const size_t rowbase = (size_t)blockIdx.x * 256;

#define DMA_C(b, c_) {                                                           \
    const float* srcbuf_ = ((c_) < 2) ? M : H;                                   \
    _Pragma("unroll")                                                            \
    for (int i = 0; i < 2; i++) {                                                \
        int rr = i * 8 + (lane >> 3);                                            \
        int jj = (lane & 7) ^ (rr & 7);                                          \
        const char* src = (const char*)(srcbuf_ + (rowbase + wave * 16 + rr) * 64) \
                          + ((c_) & 1) * 128 + jj * 16;                          \
        gload_lds16(src, (char*)&Xs[b][0] + wave * 2048 + i * 1024 + lane * 16); \
    }                                                                            \
    if (tid < 512) {                                                             \
        const short* wsrc = WF + (size_t)(c_) * 4096 + tid * 8;                  \
        gload_lds16(wsrc, (char*)&Ws[b][0] + tid * 16);                          \
    } }

    f32x4 acc[4];
#pragma unroll
    for (int nf = 0; nf < 4; nf++) acc[nf] = (f32x4){0.f, 0.f, 0.f, 0.f};

    DMA_C(0, 0);
    __syncthreads();

    for (int c = 0; c < 4; c++) {
        const int b = c & 1;
        if (c + 1 < 4) DMA_C(b ^ 1, c + 1);

        const int r = lane & 15;
        const int j0 = (lane >> 4) * 2;
        const float* abase = &Xs[b][wave * 512 + r * 32];
        f32x4 v0 = *(const f32x4*)&abase[((j0    ) ^ (r & 7)) * 4];
        f32x4 v1 = *(const f32x4*)&abase[((j0 + 1) ^ (r & 7)) * 4];
        s16x8 ah, al;
        split8(v0, v1, ah, al);
#pragma unroll
        for (int nf = 0; nf < 4; nf++) {
            s16x8 wh = *(const s16x8*)&Ws[b][(nf * 2 + 0) * 512 + lane * 8];
            s16x8 wl = *(const s16x8*)&Ws[b][(nf * 2 + 1) * 512 + lane * 8];
            acc[nf] = __builtin_amdgcn_mfma_f32_16x16x32_bf16(ah, wh, acc[nf], 0, 0, 0);
            acc[nf] = __builtin_amdgcn_mfma_f32_16x16x32_bf16(al, wh, acc[nf], 0, 0, 0);
            acc[nf] = __builtin_amdgcn_mfma_f32_16x16x32_bf16(ah, wl, acc[nf], 0, 0, 0);
        }
        __syncthreads();
    }
#undef DMA_C

    {
        const int scol = lane & 15;
        const int srow = (lane >> 4) * 4;
#pragma unroll
        for (int nf = 0; nf < 4; nf++)
#pragma unroll
            for (int ri = 0; ri < 4; ri++) {
                int cr = srow + ri;
                float* p = (cr < 8) ? &Xs[0][wave * 512 + cr * 64]
                                    : &Xs[1][wave * 512 + (cr - 8) * 64];
                p[nf * 16 + scol] = acc[nf][ri];
            }
#pragma unroll
        for (int i = 0; i < 4; i++) {
            int row = i * 4 + (lane >> 4);
            int col = (lane & 15) * 4;
            const float* p = (row < 8) ? &Xs[0][wave * 512 + row * 64]
                                       : &Xs[1][wave * 512 + (row - 8) * 64];
            f32x4 v = *(const f32x4*)&p[col];
            size_t grow = rowbase + wave * 16 + row;
            f32x4 bb = *(const f32x4*)&bias[col];
            f32x4 rr = *(const f32x4*)&resid[grow * 64 + col];
            f32x4 o;
#pragma unroll
            for (int q = 0; q < 4; q++) o[q] = fmaxf(v[q] + bb[q], 0.f) + rr[q];
            *(f32x4*)&P[grow * 64 + col] = o;
        }
    }
}

// ---------------- CSR build: one block per graph ----------------
__global__ __launch_bounds__(256) void csr_build(
    const int* __restrict__ esrc, const int* __restrict__ edst,
    int* __restrict__ csr_src, int* __restrict__ rowptr,
    int* __restrict__ degs, float* __restrict__ invdeg)
{
    __shared__ int cnt[NPG];
    __shared__ int off[NPG];
    __shared__ int cur[NPG];
    const int g = blockIdx.x, tid = threadIdx.x;
    const int ebase = g * EPG, nodebase = g * NPG;
    for (int i = tid; i < NPG; i += 256) cnt[i] = 0;
    __syncthreads();
    for (int e = tid; e < EPG; e += 256)
        atomicAdd(&cnt[edst[ebase + e] - nodebase], 1);
    __syncthreads();
    if (tid == 0) {
        int run = 0;
        for (int i = 0; i < NPG; i++) { off[i] = run; run += cnt[i]; }
    }
    __syncthreads();
    for (int i = tid; i < NPG; i += 256) {
        cur[i] = off[i];
        rowptr[nodebase + i] = off[i];
        degs[nodebase + i] = cnt[i];
        invdeg[nodebase + i] = 1.f / fmaxf((float)cnt[i], 1.f);
    }
    __syncthreads();
    for (int e = tid; e < EPG; e += 256) {
        int ld = edst[ebase + e] - nodebase;
        int p = atomicAdd(&cur[ld], 1);
        csr_src[ebase + p] = esrc[ebase + e] - nodebase;  // local src
    }
}

// ---------------- layer-1 aggregate+combine (reads A [N,128]) ----------------
__global__ __launch_bounds__(1024) void agg_lds(
    const float* __restrict__ A,
    const int* __restrict__ csr_src, const int* __restrict__ rowptr,
    const int* __restrict__ degs, const float* __restrict__ invdeg,
    const float* __restrict__ bias,
    float* __restrict__ Xout)
{
    __shared__ float y[NPG * 64];     // 102400 B
    __shared__ int   csr_l[EPG];      // 25600 B
    const int g = blockIdx.x, tid = threadIdx.x;
    const int ebase = g * EPG, nodebase = g * NPG;

    for (int idx = tid; idx < NPG * 16; idx += 1024) {
        int node = idx >> 4, c4 = (idx & 15) * 4;
        *(float4*)&y[node * 64 + c4] =
            *(const float4*)&A[(size_t)(nodebase + node) * 128 + c4];
    }
    for (int e = tid; e < EPG; e += 1024) csr_l[e] = csr_src[ebase + e];
    __syncthreads();

    const int wave = tid >> 6, lane = tid & 63;
    for (int node = wave; node < NPG; node += 16) {
        const int start = rowptr[nodebase + node];
        const int dg = degs[nodebase + node];
        float acc = 0.f;
        int j = 0;
        for (; j + 4 <= dg; j += 4) {
            int s0 = csr_l[start + j];
            int s1 = csr_l[start + j + 1];
            int s2 = csr_l[start + j + 2];
            int s3 = csr_l[start + j + 3];
            acc += y[s0 * 64 + lane] + y[s1 * 64 + lane]
                 + y[s2 * 64 + lane] + y[s3 * 64 + lane];
        }
        for (; j < dg; j++) acc += y[csr_l[start + j] * 64 + lane];

        float v = acc * invdeg[nodebase + node] + bias[lane]
                + A[(size_t)(nodebase + node) * 128 + 64 + lane];
        Xout[(size_t)(nodebase + node) * 64 + lane] = fmaxf(v, 0.f);
    }
}

// ---------------- input-side aggregation: M = mean-agg(H) --------------------
__global__ __launch_bounds__(1024) void agg_in(
    const float* __restrict__ H,
    const int* __restrict__ csr_src, const int* __restrict__ rowptr,
    const int* __restrict__ degs, const float* __restrict__ invdeg,
    float* __restrict__ M)
{
    __shared__ float y[NPG * 64];     // 102400 B
    __shared__ int   csr_l[EPG];      // 25600 B
    const int g = blockIdx.x, tid = threadIdx.x;
    const int ebase = g * EPG, nodebase = g * NPG;

    for (int idx = tid; idx < NPG * 16; idx += 1024) {
        int node = idx >> 4, c4 = (idx & 15) * 4;
        *(float4*)&y[node * 64 + c4] =
            *(const float4*)&H[(size_t)(nodebase + node) * 64 + c4];
    }
    for (int e = tid; e < EPG; e += 1024) csr_l[e] = csr_src[ebase + e];
    __syncthreads();

    const int wave = tid >> 6, lane = tid & 63;
    for (int node = wave; node < NPG; node += 16) {
        const int start = rowptr[nodebase + node];
        const int dg = degs[nodebase + node];
        float acc = 0.f;
        int j = 0;
        for (; j + 4 <= dg; j += 4) {
            int s0 = csr_l[start + j];
            int s1 = csr_l[start + j + 1];
            int s2 = csr_l[start + j + 2];
            int s3 = csr_l[start + j + 3];
            acc += y[s0 * 64 + lane] + y[s1 * 64 + lane]
                 + y[s2 * 64 + lane] + y[s3 * 64 + lane];
        }
        for (; j < dg; j++) acc += y[csr_l[start + j] * 64 + lane];

        M[(size_t)(nodebase + node) * 64 + lane] = acc * invdeg[nodebase + node];
    }
}

// ------- score+topk+pool+classifier, LDS-staged (agg_lds shape) -------------
__global__ __launch_bounds__(1024) void score_pool3(
    const float* __restrict__ X3,
    const int* __restrict__ esrc, const int* __restrict__ edst,
    const float* __restrict__ Wpr, const float* __restrict__ bpr,
    const float* __restrict__ Wpo,
    const float* __restrict__ Wlin, const float* __restrict__ blin,
    float* __restrict__ out)
{
    __shared__ float y[NPG * 64];        // 102400 B (X3 slice)
    __shared__ float t0s[NPG], ss[NPG], wsel[NPG];
    __shared__ float wprs[64], wpos[64];
    __shared__ float pp[16 * 64];
    __shared__ float pooled[64];
    __shared__ float lgs[2];
    const int g = blockIdx.x, tid = threadIdx.x;
    const int nodebase = g * NPG, ebase = g * EPG;

    if (tid < 64) { wprs[tid] = Wpr[tid]; wpos[tid] = Wpo[tid]; }
    // stage X3 slice (coalesced float4)
    for (int idx = tid; idx < NPG * 16; idx += 1024) {
        int node = idx >> 4, c4 = (idx & 15) * 4;
        *(float4*)&y[node * 64 + c4] =
            *(const float4*)&X3[(size_t)(nodebase + node) * 64 + c4];
    }
    __syncthreads();

    // phase 1: per-node dots from LDS, bank-staggered d = (tid+i)&63
    if (tid < NPG) {
        float a0 = 0.f, a1 = 0.f;
        const float* yr = &y[tid * 64];
#pragma unroll
        for (int i = 0; i < 64; i++) {
            int d = (tid + i) & 63;
            float v = yr[d];
            a0 += v * wprs[d];
            a1 += v * wpos[d];
        }
        t0s[tid] = a0;
        ss[tid] = bpr[0] + a1;
    }
    __syncthreads();
    // phase 2: edge aggregation via LDS atomics (coalesced global edge reads)
    for (int e = tid; e < EPG; e += 1024) {
        int ls = esrc[ebase + e] - nodebase;
        int ld = edst[ebase + e] - nodebase;
        atomicAdd(&ss[ld], t0s[ls]);
    }
    __syncthreads();
    // phase 3: stable top-k by counting (matches lax.top_k tie-breaking)
    if (tid < NPG) {
        float si = ss[tid];
        int cnt = 0;
        for (int j = 0; j < NPG; j++) {
            float sj = ss[j];
            cnt += (sj > si) || (sj == si && j < tid);
        }
        wsel[tid] = (cnt < KSEL) ? tanhf(si) * (1.f / KSEL) : 0.f;
    }
    __syncthreads();
    // phase 4: tanh-weighted mean pool from LDS (lane = dim, conflict-free)
    {
        const int d = tid & 63, part = tid >> 6;
        float a = 0.f;
        for (int i = part * 25; i < part * 25 + 25; i++)
            a += wsel[i] * y[i * 64 + d];
        pp[part * 64 + d] = a;
    }
    __syncthreads();
    if (tid < 64) {
        float s = 0.f;
#pragma unroll
        for (int i = 0; i < 16; i++) s += pp[i * 64 + tid];
        pooled[tid] = s;
    }
    __syncthreads();
    if (tid < 2) {
        float l = blin[tid];
        for (int d = 0; d < 64; d++) l += pooled[d] * Wlin[d * 2 + tid];
        lgs[tid] = l;
    }
    __syncthreads();
    if (tid < 2) {
        float m = fmaxf(lgs[0], lgs[1]);
        float lse = m + logf(expf(lgs[0] - m) + expf(lgs[1] - m));
        out[g * 2 + tid] = lgs[tid] - lse;
    }
}

extern "C" void kernel_launch(void* const* d_in, const int* in_sizes, int n_in,
                              void* d_out, int out_size, void* d_ws, size_t ws_size,
                              hipStream_t stream) {
    const float* x    = (const float*)d_in[0];
    const int*   eidx = (const int*)d_in[1];
    const float* W1l  = (const float*)d_in[3];
    const float* W1r  = (const float*)d_in[4];
    const float* b1   = (const float*)d_in[5];
    const float* W2l  = (const float*)d_in[6];
    const float* W2r  = (const float*)d_in[7];
    const float* b2   = (const float*)d_in[8];
    const float* W3l  = (const float*)d_in[9];
    const float* W3r  = (const float*)d_in[10];
    const float* b3   = (const float*)d_in[11];
    const float* Wpr  = (const float*)d_in[12];
    const float* bpr  = (const float*)d_in[13];
    const float* Wpo  = (const float*)d_in[14];
    const float* Wlin = (const float*)d_in[15];
    const float* blin = (const float*)d_in[16];

    const int N = in_sizes[0] / F_IN;       // 204800
    const int E = in_sizes[1] / 2;          // 3276800
    const int B = N / NPG;                  // 512
    const int* esrc = eidx;
    const int* edst = eidx + E;

    float* ws = (float*)d_ws;
    float* A      = ws;                                  // [N,128] layer-1 yz
    float* P0     = A + (size_t)N * 128;                 // [N,64]
    float* P1     = P0 + (size_t)N * 64;                 // [N,64]
    float* Mb     = P1 + (size_t)N * 64;                 // [N,64] mean-agg
    float* invdeg = Mb + (size_t)N * 64;                 // [N]
    short* WF1    = (short*)(invdeg + N);                // 7*8*2*512 shorts
    short* WFc2   = WF1 + 57344;                         // 4*4*2*512 shorts
    short* WFc3   = WFc2 + 16384;
    int*   csr    = (int*)(WFc3 + 16384);                // [E] local src by dst
    int*   rowptr = csr + E;                             // [N]
    int*   degs   = rowptr + N;                          // [N]

    pack_wf<<<(7 * 4096 + 255) / 256, 256, 0, stream>>>(W1l, W1r, WF1, 200, 7);
    pack_wf4<<<(4 * 2048 + 255) / 256, 256, 0, stream>>>(W2l, W2r, WFc2);
    pack_wf4<<<(4 * 2048 + 255) / 256, 256, 0, stream>>>(W3l, W3r, WFc3);

    // CSR once (shared by all layers)
    csr_build<<<B, 256, 0, stream>>>(esrc, edst, csr, rowptr, degs, invdeg);

    // layer 1: yz = x @ [W1l|W1r] -> A; x1 = relu(agg(y)+b+z) -> P0
    gemm_lds<200, 200, 6, 8><<<N / 128, 256, 0, stream>>>(x, WF1, A);
    agg_lds<<<B, 1024, 0, stream>>>(A, csr, rowptr, degs, invdeg, b1, P0);

    // layer 2 (m-form): M = mean-agg(P0); x2 = relu([M|P0]@Wc2 + b2) + P0 -> P1
    agg_in<<<B, 1024, 0, stream>>>(P0, csr, rowptr, degs, invdeg, Mb);
    combine_gemm<<<N / 256, 1024, 0, stream>>>(Mb, P0, WFc2, b2, P0, P1);

    // layer 3 (m-form): M = mean-agg(P1); x3 = relu([M|P1]@Wc3 + b3) + P1 -> P0
    agg_in<<<B, 1024, 0, stream>>>(P1, csr, rowptr, degs, invdeg, Mb);
    combine_gemm<<<N / 256, 1024, 0, stream>>>(Mb, P1, WFc3, b3, P1, P0);

    // score + top-k + pool + classifier (LDS-staged)
    score_pool3<<<B, 1024, 0, stream>>>(P0, esrc, edst,
                                        Wpr, bpr, Wpo, Wlin, blin,
                                        (float*)d_out);
}

// Round 16
// 438.237 us; speedup vs baseline: 1.2001x; 1.0628x over previous
//
#include <hip/hip_runtime.h>
#include <hip/hip_bf16.h>
#include <math.h>

#define F_IN 200
#define HDIM 64
#define NPG  400
#define EPG  6400
#define KSEL 200   // NPG/2

typedef __attribute__((ext_vector_type(4))) float f32x4;
typedef __attribute__((ext_vector_type(8))) short s16x8;

__device__ __forceinline__ void gload_lds16(const void* g, void* l) {
    __builtin_amdgcn_global_load_lds(
        (const __attribute__((address_space(1))) void*)g,
        (__attribute__((address_space(3))) void*)l, 16, 0, 0);
}

// RNE float -> bf16 bits
__device__ __forceinline__ unsigned int bf16_rne(float x) {
    unsigned int b = __float_as_uint(x);
    return (b + 0x7FFFu + ((b >> 16) & 1u)) >> 16;
}

// split x into bf16 hi + bf16 lo (x ~= hi + lo, rel err ~2^-17)
__device__ __forceinline__ void split8(f32x4 v0, f32x4 v1, s16x8& h, s16x8& l) {
    float x[8] = {v0.x, v0.y, v0.z, v0.w, v1.x, v1.y, v1.z, v1.w};
#pragma unroll
    for (int j = 0; j < 8; j++) {
        unsigned int hb = bf16_rne(x[j]);
        float hf = __uint_as_float(hb << 16);
        float r = x[j] - hf;
        unsigned int lb = bf16_rne(r);
        h[j] = (short)hb;
        l[j] = (short)lb;
    }
}

// ---------------- pack W ([K,64]|[K,64] fp32) -> fragment-ordered bf16 pairs --
__global__ void pack_wf(const float* __restrict__ Wl, const float* __restrict__ Wr,
                        short* __restrict__ WF, int K, int KC) {
    int idx = blockIdx.x * blockDim.x + threadIdx.x;
    if (idx >= KC * 4096) return;
    int j    = idx & 7;
    int lane = (idx >> 3) & 63;
    int nf   = (idx >> 9) & 7;
    int kc   = idx >> 12;
    int k = kc * 32 + (lane >> 4) * 8 + j;
    int n = nf * 16 + (lane & 15);
    float v = 0.f;
    if (k < K) v = (n < 64) ? Wl[k * 64 + n] : Wr[k * 64 + (n - 64)];
    unsigned int hb = bf16_rne(v);
    float hf = __uint_as_float(hb << 16);
    unsigned int lb = bf16_rne(v - hf);
    WF[(size_t)((kc * 8 + nf) * 2 + 0) * 512 + lane * 8 + j] = (short)hb;
    WF[(size_t)((kc * 8 + nf) * 2 + 1) * 512 + lane * 8 + j] = (short)lb;
}

// ---------------- pack combine-W: [Wl;Wr] (K=128, 4 n-frags) ----------------
__global__ void pack_wf4(const float* __restrict__ Wl, const float* __restrict__ Wr,
                         short* __restrict__ WF) {
    int idx = blockIdx.x * blockDim.x + threadIdx.x;
    if (idx >= 4 * 2048) return;                 // 4 kc x 4 nf x 512
    int j    = idx & 7;
    int lane = (idx >> 3) & 63;
    int nf   = (idx >> 9) & 3;
    int kc   = idx >> 11;
    int k = kc * 32 + (lane >> 4) * 8 + j;
    int n = nf * 16 + (lane & 15);
    float v = (k < 64) ? Wl[k * 64 + n] : Wr[(k - 64) * 64 + n];
    unsigned int hb = bf16_rne(v);
    float hf = __uint_as_float(hb << 16);
    unsigned int lb = bf16_rne(v - hf);
    WF[(size_t)((kc * 4 + nf) * 2 + 0) * 512 + lane * 8 + j] = (short)hb;
    WF[(size_t)((kc * 4 + nf) * 2 + 1) * 512 + lane * 8 + j] = (short)lb;
}

// ---------------- layer-1 MFMA GEMM (R11-proven) ----------------------------
template <int K, int LDX, int KC, int TAIL>
__global__ __launch_bounds__(256) void gemm_lds(const float* __restrict__ X,
                                                const short* __restrict__ WF,
                                                float* __restrict__ O) {
    __shared__ float Xs[2][128 * 32];    // 2 x 16 KB
    __shared__ short Ws[2][8 * 2 * 512]; // 2 x 16 KB
    const int tid  = threadIdx.x;
    const int lane = tid & 63;
    const int wave = tid >> 6;
    const size_t rowbase = (size_t)blockIdx.x * 128;
    const f32x4 zero4 = (f32x4){0.f, 0.f, 0.f, 0.f};

    const int srow_off = wave * 32 + (lane >> 3);
    const int sbyte    = 16 * ((lane & 7) ^ (lane >> 3));

#define DMA_CHUNK(b, kc_) {                                                      \
    _Pragma("unroll")                                                            \
    for (int j = 0; j < 4; j++) {                                                \
        const char* xsrc = (const char*)X +                                      \
            (rowbase + srow_off + j * 8) * (size_t)(LDX * 4) + (kc_) * 128 + sbyte; \
        gload_lds16(xsrc, (char*)&Xs[b][0] + wave * 4096 + j * 1024);            \
        const short* wsrc = WF + (size_t)(kc_) * 8192 + wave * 2048 + j * 512 + lane * 8; \
        gload_lds16(wsrc, (char*)&Ws[b][0] + wave * 4096 + j * 1024);            \
    } }

    f32x4 acc[2][8];
#pragma unroll
    for (int m = 0; m < 2; m++)
#pragma unroll
        for (int nf = 0; nf < 8; nf++) acc[m][nf] = zero4;

    DMA_CHUNK(0, 0);
    __syncthreads();

    for (int kc = 0; kc < KC; kc++) {
        const int b = kc & 1;
        if (kc + 1 < KC) DMA_CHUNK(b ^ 1, kc + 1);

        s16x8 ah[2], al[2];
#pragma unroll
        for (int m = 0; m < 2; m++) {
            const int lr = wave * 32 + m * 16 + (lane & 15);
            const int g0 = (lane >> 4) * 2;
            f32x4 v0 = *(const f32x4*)&Xs[b][lr * 32 + 4 * (g0 ^ (lane & 7))];
            f32x4 v1 = *(const f32x4*)&Xs[b][lr * 32 + 4 * ((g0 + 1) ^ (lane & 7))];
            split8(v0, v1, ah[m], al[m]);
        }
#pragma unroll
        for (int nf = 0; nf < 8; nf++) {
            s16x8 wh = *(const s16x8*)&Ws[b][(nf * 2 + 0) * 512 + lane * 8];
            s16x8 wl = *(const s16x8*)&Ws[b][(nf * 2 + 1) * 512 + lane * 8];
#pragma unroll
            for (int m = 0; m < 2; m++) {
                acc[m][nf] = __builtin_amdgcn_mfma_f32_16x16x32_bf16(ah[m], wh, acc[m][nf], 0, 0, 0);
                acc[m][nf] = __builtin_amdgcn_mfma_f32_16x16x32_bf16(al[m], wh, acc[m][nf], 0, 0, 0);
                acc[m][nf] = __builtin_amdgcn_mfma_f32_16x16x32_bf16(ah[m], wl, acc[m][nf], 0, 0, 0);
            }
        }
        __syncthreads();
    }
#undef DMA_CHUNK

    if constexpr (TAIL > 0) {
        s16x8 ah[2], al[2];
#pragma unroll
        for (int m = 0; m < 2; m++) {
            const size_t row = rowbase + wave * 32 + m * 16 + (lane & 15);
            const int k0 = KC * 32 + (lane >> 4) * 8;
            f32x4 v0 = (k0 + 4 <= K) ? *(const f32x4*)&X[row * (size_t)LDX + k0] : zero4;
            f32x4 v1 = (k0 + 8 <= K) ? *(const f32x4*)&X[row * (size_t)LDX + k0 + 4] : zero4;
            split8(v0, v1, ah[m], al[m]);
        }
#pragma unroll
        for (int nf = 0; nf < 8; nf++) {
            s16x8 wh = *(const s16x8*)&WF[(size_t)((KC * 8 + nf) * 2 + 0) * 512 + lane * 8];
            s16x8 wl = *(const s16x8*)&WF[(size_t)((KC * 8 + nf) * 2 + 1) * 512 + lane * 8];
#pragma unroll
            for (int m = 0; m < 2; m++) {
                acc[m][nf] = __builtin_amdgcn_mfma_f32_16x16x32_bf16(ah[m], wh, acc[m][nf], 0, 0, 0);
                acc[m][nf] = __builtin_amdgcn_mfma_f32_16x16x32_bf16(al[m], wh, acc[m][nf], 0, 0, 0);
                acc[m][nf] = __builtin_amdgcn_mfma_f32_16x16x32_bf16(ah[m], wl, acc[m][nf], 0, 0, 0);
            }
        }
    }

    float* cs0 = &Xs[0][wave * 1024];
    float* cs1 = &Xs[1][wave * 1024];
#pragma unroll
    for (int m = 0; m < 2; m++) {
        const int scol = lane & 15;
        const int srow = (lane >> 4) * 4;
#pragma unroll
        for (int nf = 0; nf < 8; nf++)
#pragma unroll
            for (int r = 0; r < 4; r++) {
                int cr = srow + r;
                float* p = (cr < 8) ? cs0 + cr * 128 : cs1 + (cr - 8) * 128;
                p[nf * 16 + scol] = acc[m][nf][r];
            }
#pragma unroll
        for (int ps = 0; ps < 8; ps++) {
            int row = ps * 2 + (lane >> 5);
            const float* p = (row < 8) ? cs0 + row * 128 : cs1 + (row - 8) * 128;
            f32x4 v = *(const f32x4*)&p[(lane & 31) * 4];
            *(f32x4*)&O[(rowbase + wave * 32 + m * 16 + row) * 128 + (lane & 31) * 4] = v;
        }
    }
}

// ------- combine GEMM, single-shot: P = relu([M|H]@Wc+b)+resid --------------
// 64 rows/block, 256 thr (4 waves x one 16-row m-frag). LDS = Xs[4][64x32] +
// Ws[4][4096sh] = 64 KB (2 blocks/CU). All 4 chunks DMA'd upfront (R12-proven
// per-chunk addressing, wave-uniform srcbuf), ONE barrier, 48 MFMAs straight.
// X reads and epilogue restage are wave-private (no further barriers).
__global__ __launch_bounds__(256) void combine_ss(
    const float* __restrict__ M, const float* __restrict__ H,
    const short* __restrict__ WF, const float* __restrict__ bias,
    const float* __restrict__ resid, float* __restrict__ P)
{
    __shared__ float Xs[4][64 * 32];     // 4 x 8 KB
    __shared__ short Ws[4][4096];        // 4 x 8 KB
    const int tid  = threadIdx.x;
    const int lane = tid & 63;
    const int wave = tid >> 6;
    const size_t rowbase = (size_t)blockIdx.x * 64;

    // ---- DMA all 4 chunks (wave-uniform srcbuf per chunk) ----
#pragma unroll
    for (int c = 0; c < 4; c++) {
        const float* srcbuf = (c < 2) ? M : H;      // wave-uniform select
#pragma unroll
        for (int i = 0; i < 2; i++) {
            int rr = i * 8 + (lane >> 3);
            int jj = (lane & 7) ^ (rr & 7);
            const char* src = (const char*)(srcbuf + (rowbase + wave * 16 + rr) * 64)
                              + (c & 1) * 128 + jj * 16;
            gload_lds16(src, (char*)&Xs[c][0] + wave * 2048 + i * 1024 + lane * 16);
        }
#pragma unroll
        for (int t = 0; t < 2; t++) {
            int idx = t * 256 + tid;
            const short* wsrc = WF + (size_t)c * 4096 + idx * 8;
            gload_lds16(wsrc, (char*)&Ws[c][0] + idx * 16);
        }
    }
    __syncthreads();

    f32x4 acc[4];
#pragma unroll
    for (int nf = 0; nf < 4; nf++) acc[nf] = (f32x4){0.f, 0.f, 0.f, 0.f};

    const int r = lane & 15;
    const int j0 = (lane >> 4) * 2;
#pragma unroll
    for (int kc = 0; kc < 4; kc++) {
        const float* abase = &Xs[kc][wave * 512 + r * 32];
        f32x4 v0 = *(const f32x4*)&abase[((j0    ) ^ (r & 7)) * 4];
        f32x4 v1 = *(const f32x4*)&abase[((j0 + 1) ^ (r & 7)) * 4];
        s16x8 ah, al;
        split8(v0, v1, ah, al);
#pragma unroll
        for (int nf = 0; nf < 4; nf++) {
            s16x8 wh = *(const s16x8*)&Ws[kc][(nf * 2 + 0) * 512 + lane * 8];
            s16x8 wl = *(const s16x8*)&Ws[kc][(nf * 2 + 1) * 512 + lane * 8];
            acc[nf] = __builtin_amdgcn_mfma_f32_16x16x32_bf16(ah, wh, acc[nf], 0, 0, 0);
            acc[nf] = __builtin_amdgcn_mfma_f32_16x16x32_bf16(al, wh, acc[nf], 0, 0, 0);
            acc[nf] = __builtin_amdgcn_mfma_f32_16x16x32_bf16(ah, wl, acc[nf], 0, 0, 0);
        }
    }

    // ---- epilogue: wave-private restage, fused bias/relu/resid ----
    {
        float* cs0 = &Xs[0][wave * 512];   // rows 0..7 (16x64 halves)
        float* cs1 = &Xs[1][wave * 512];   // rows 8..15
        const int scol = lane & 15;
        const int srow = (lane >> 4) * 4;
#pragma unroll
        for (int nf = 0; nf < 4; nf++)
#pragma unroll
            for (int ri = 0; ri < 4; ri++) {
                int cr = srow + ri;
                float* p = (cr < 8) ? cs0 + cr * 64 : cs1 + (cr - 8) * 64;
                p[nf * 16 + scol] = acc[nf][ri];
            }
#pragma unroll
        for (int i = 0; i < 4; i++) {
            int row = i * 4 + (lane >> 4);
            int col = (lane & 15) * 4;
            const float* p = (row < 8) ? cs0 + row * 64 : cs1 + (row - 8) * 64;
            f32x4 v = *(const f32x4*)&p[col];
            size_t grow = rowbase + wave * 16 + row;
            f32x4 bb = *(const f32x4*)&bias[col];
            f32x4 rr = *(const f32x4*)&resid[grow * 64 + col];
            f32x4 o;
#pragma unroll
            for (int q = 0; q < 4; q++) o[q] = fmaxf(v[q] + bb[q], 0.f) + rr[q];
            *(f32x4*)&P[grow * 64 + col] = o;
        }
    }
}

// ---------------- CSR build: one block per graph ----------------
__global__ __launch_bounds__(256) void csr_build(
    const int* __restrict__ esrc, const int* __restrict__ edst,
    int* __restrict__ csr_src, int* __restrict__ rowptr,
    int* __restrict__ degs, float* __restrict__ invdeg)
{
    __shared__ int cnt[NPG];
    __shared__ int off[NPG];
    __shared__ int cur[NPG];
    const int g = blockIdx.x, tid = threadIdx.x;
    const int ebase = g * EPG, nodebase = g * NPG;
    for (int i = tid; i < NPG; i += 256) cnt[i] = 0;
    __syncthreads();
    for (int e = tid; e < EPG; e += 256)
        atomicAdd(&cnt[edst[ebase + e] - nodebase], 1);
    __syncthreads();
    if (tid == 0) {
        int run = 0;
        for (int i = 0; i < NPG; i++) { off[i] = run; run += cnt[i]; }
    }
    __syncthreads();
    for (int i = tid; i < NPG; i += 256) {
        cur[i] = off[i];
        rowptr[nodebase + i] = off[i];
        degs[nodebase + i] = cnt[i];
        invdeg[nodebase + i] = 1.f / fmaxf((float)cnt[i], 1.f);
    }
    __syncthreads();
    for (int e = tid; e < EPG; e += 256) {
        int ld = edst[ebase + e] - nodebase;
        int p = atomicAdd(&cur[ld], 1);
        csr_src[ebase + p] = esrc[ebase + e] - nodebase;  // local src
    }
}

// ---------------- layer-1 aggregate+combine (reads A [N,128]) ----------------
__global__ __launch_bounds__(1024) void agg_lds(
    const float* __restrict__ A,
    const int* __restrict__ csr_src, const int* __restrict__ rowptr,
    const int* __restrict__ degs, const float* __restrict__ invdeg,
    const float* __restrict__ bias,
    float* __restrict__ Xout)
{
    __shared__ float y[NPG * 64];     // 102400 B
    __shared__ int   csr_l[EPG];      // 25600 B
    const int g = blockIdx.x, tid = threadIdx.x;
    const int ebase = g * EPG, nodebase = g * NPG;

    for (int idx = tid; idx < NPG * 16; idx += 1024) {
        int node = idx >> 4, c4 = (idx & 15) * 4;
        *(float4*)&y[node * 64 + c4] =
            *(const float4*)&A[(size_t)(nodebase + node) * 128 + c4];
    }
    for (int e = tid; e < EPG; e += 1024) csr_l[e] = csr_src[ebase + e];
    __syncthreads();

    const int wave = tid >> 6, lane = tid & 63;
    for (int node = wave; node < NPG; node += 16) {
        const int start = rowptr[nodebase + node];
        const int dg = degs[nodebase + node];
        float acc = 0.f;
        int j = 0;
        for (; j + 4 <= dg; j += 4) {
            int s0 = csr_l[start + j];
            int s1 = csr_l[start + j + 1];
            int s2 = csr_l[start + j + 2];
            int s3 = csr_l[start + j + 3];
            acc += y[s0 * 64 + lane] + y[s1 * 64 + lane]
                 + y[s2 * 64 + lane] + y[s3 * 64 + lane];
        }
        for (; j < dg; j++) acc += y[csr_l[start + j] * 64 + lane];

        float v = acc * invdeg[nodebase + node] + bias[lane]
                + A[(size_t)(nodebase + node) * 128 + 64 + lane];
        Xout[(size_t)(nodebase + node) * 64 + lane] = fmaxf(v, 0.f);
    }
}

// ---------------- input-side aggregation: M = mean-agg(H) --------------------
__global__ __launch_bounds__(1024) void agg_in(
    const float* __restrict__ H,
    const int* __restrict__ csr_src, const int* __restrict__ rowptr,
    const int* __restrict__ degs, const float* __restrict__ invdeg,
    float* __restrict__ M)
{
    __shared__ float y[NPG * 64];     // 102400 B
    __shared__ int   csr_l[EPG];      // 25600 B
    const int g = blockIdx.x, tid = threadIdx.x;
    const int ebase = g * EPG, nodebase = g * NPG;

    for (int idx = tid; idx < NPG * 16; idx += 1024) {
        int node = idx >> 4, c4 = (idx & 15) * 4;
        *(float4*)&y[node * 64 + c4] =
            *(const float4*)&H[(size_t)(nodebase + node) * 64 + c4];
    }
    for (int e = tid; e < EPG; e += 1024) csr_l[e] = csr_src[ebase + e];
    __syncthreads();

    const int wave = tid >> 6, lane = tid & 63;
    for (int node = wave; node < NPG; node += 16) {
        const int start = rowptr[nodebase + node];
        const int dg = degs[nodebase + node];
        float acc = 0.f;
        int j = 0;
        for (; j + 4 <= dg; j += 4) {
            int s0 = csr_l[start + j];
            int s1 = csr_l[start + j + 1];
            int s2 = csr_l[start + j + 2];
            int s3 = csr_l[start + j + 3];
            acc += y[s0 * 64 + lane] + y[s1 * 64 + lane]
                 + y[s2 * 64 + lane] + y[s3 * 64 + lane];
        }
        for (; j < dg; j++) acc += y[csr_l[start + j] * 64 + lane];

        M[(size_t)(nodebase + node) * 64 + lane] = acc * invdeg[nodebase + node];
    }
}

// ------- score+topk+pool+classifier, LDS-staged (R15-proven) ----------------
__global__ __launch_bounds__(1024) void score_pool3(
    const float* __restrict__ X3,
    const int* __restrict__ esrc, const int* __restrict__ edst,
    const float* __restrict__ Wpr, const float* __restrict__ bpr,
    const float* __restrict__ Wpo,
    const float* __restrict__ Wlin, const float* __restrict__ blin,
    float* __restrict__ out)
{
    __shared__ float y[NPG * 64];        // 102400 B (X3 slice)
    __shared__ float t0s[NPG], ss[NPG], wsel[NPG];
    __shared__ float wprs[64], wpos[64];
    __shared__ float pp[16 * 64];
    __shared__ float pooled[64];
    __shared__ float lgs[2];
    const int g = blockIdx.x, tid = threadIdx.x;
    const int nodebase = g * NPG, ebase = g * EPG;

    if (tid < 64) { wprs[tid] = Wpr[tid]; wpos[tid] = Wpo[tid]; }
    for (int idx = tid; idx < NPG * 16; idx += 1024) {
        int node = idx >> 4, c4 = (idx & 15) * 4;
        *(float4*)&y[node * 64 + c4] =
            *(const float4*)&X3[(size_t)(nodebase + node) * 64 + c4];
    }
    __syncthreads();

    if (tid < NPG) {
        float a0 = 0.f, a1 = 0.f;
        const float* yr = &y[tid * 64];
#pragma unroll
        for (int i = 0; i < 64; i++) {
            int d = (tid + i) & 63;
            float v = yr[d];
            a0 += v * wprs[d];
            a1 += v * wpos[d];
        }
        t0s[tid] = a0;
        ss[tid] = bpr[0] + a1;
    }
    __syncthreads();
    for (int e = tid; e < EPG; e += 1024) {
        int ls = esrc[ebase + e] - nodebase;
        int ld = edst[ebase + e] - nodebase;
        atomicAdd(&ss[ld], t0s[ls]);
    }
    __syncthreads();
    if (tid < NPG) {
        float si = ss[tid];
        int cnt = 0;
        for (int j = 0; j < NPG; j++) {
            float sj = ss[j];
            cnt += (sj > si) || (sj == si && j < tid);
        }
        wsel[tid] = (cnt < KSEL) ? tanhf(si) * (1.f / KSEL) : 0.f;
    }
    __syncthreads();
    {
        const int d = tid & 63, part = tid >> 6;
        float a = 0.f;
        for (int i = part * 25; i < part * 25 + 25; i++)
            a += wsel[i] * y[i * 64 + d];
        pp[part * 64 + d] = a;
    }
    __syncthreads();
    if (tid < 64) {
        float s = 0.f;
#pragma unroll
        for (int i = 0; i < 16; i++) s += pp[i * 64 + tid];
        pooled[tid] = s;
    }
    __syncthreads();
    if (tid < 2) {
        float l = blin[tid];
        for (int d = 0; d < 64; d++) l += pooled[d] * Wlin[d * 2 + tid];
        lgs[tid] = l;
    }
    __syncthreads();
    if (tid < 2) {
        float m = fmaxf(lgs[0], lgs[1]);
        float lse = m + logf(expf(lgs[0] - m) + expf(lgs[1] - m));
        out[g * 2 + tid] = lgs[tid] - lse;
    }
}

extern "C" void kernel_launch(void* const* d_in, const int* in_sizes, int n_in,
                              void* d_out, int out_size, void* d_ws, size_t ws_size,
                              hipStream_t stream) {
    const float* x    = (const float*)d_in[0];
    const int*   eidx = (const int*)d_in[1];
    const float* W1l  = (const float*)d_in[3];
    const float* W1r  = (const float*)d_in[4];
    const float* b1   = (const float*)d_in[5];
    const float* W2l  = (const float*)d_in[6];
    const float* W2r  = (const float*)d_in[7];
    const float* b2   = (const float*)d_in[8];
    const float* W3l  = (const float*)d_in[9];
    const float* W3r  = (const float*)d_in[10];
    const float* b3   = (const float*)d_in[11];
    const float* Wpr  = (const float*)d_in[12];
    const float* bpr  = (const float*)d_in[13];
    const float* Wpo  = (const float*)d_in[14];
    const float* Wlin = (const float*)d_in[15];
    const float* blin = (const float*)d_in[16];

    const int N = in_sizes[0] / F_IN;       // 204800
    const int E = in_sizes[1] / 2;          // 3276800
    const int B = N / NPG;                  // 512
    const int* esrc = eidx;
    const int* edst = eidx + E;

    float* ws = (float*)d_ws;
    float* A      = ws;                                  // [N,128] layer-1 yz
    float* P0     = A + (size_t)N * 128;                 // [N,64]
    float* P1     = P0 + (size_t)N * 64;                 // [N,64]
    float* Mb     = P1 + (size_t)N * 64;                 // [N,64] mean-agg
    float* invdeg = Mb + (size_t)N * 64;                 // [N]
    short* WF1    = (short*)(invdeg + N);                // 7*8*2*512 shorts
    short* WFc2   = WF1 + 57344;                         // 4*4*2*512 shorts
    short* WFc3   = WFc2 + 16384;
    int*   csr    = (int*)(WFc3 + 16384);                // [E] local src by dst
    int*   rowptr = csr + E;                             // [N]
    int*   degs   = rowptr + N;                          // [N]

    pack_wf<<<(7 * 4096 + 255) / 256, 256, 0, stream>>>(W1l, W1r, WF1, 200, 7);
    pack_wf4<<<(4 * 2048 + 255) / 256, 256, 0, stream>>>(W2l, W2r, WFc2);
    pack_wf4<<<(4 * 2048 + 255) / 256, 256, 0, stream>>>(W3l, W3r, WFc3);

    // CSR once (shared by all layers)
    csr_build<<<B, 256, 0, stream>>>(esrc, edst, csr, rowptr, degs, invdeg);

    // layer 1: yz = x @ [W1l|W1r] -> A; x1 = relu(agg(y)+b+z) -> P0
    gemm_lds<200, 200, 6, 8><<<N / 128, 256, 0, stream>>>(x, WF1, A);
    agg_lds<<<B, 1024, 0, stream>>>(A, csr, rowptr, degs, invdeg, b1, P0);

    // layer 2 (m-form): M = mean-agg(P0); x2 = relu([M|P0]@Wc2 + b2) + P0 -> P1
    agg_in<<<B, 1024, 0, stream>>>(P0, csr, rowptr, degs, invdeg, Mb);
    combine_ss<<<N / 64, 256, 0, stream>>>(Mb, P0, WFc2, b2, P0, P1);

    // layer 3 (m-form): M = mean-agg(P1); x3 = relu([M|P1]@Wc3 + b3) + P1 -> P0
    agg_in<<<B, 1024, 0, stream>>>(P1, csr, rowptr, degs, invdeg, Mb);
    combine_ss<<<N / 64, 256, 0, stream>>>(Mb, P1, WFc3, b3, P1, P0);

    // score + top-k + pool + classifier (LDS-staged)
    score_pool3<<<B, 1024, 0, stream>>>(P0, esrc, edst,
                                        Wpr, bpr, Wpo, Wlin, blin,
                                        (float*)d_out);
}